// Round 2
// baseline (804.123 us; speedup 1.0000x reference)
//
#include <hip/hip_runtime.h>
#include <stdint.h>

#define H_DIM 4096
#define I_DIM 11008
#define T_DIM 4096

typedef int i32x4 __attribute__((ext_vector_type(4)));
typedef const void __attribute__((address_space(1))) gvoid_t;
typedef void __attribute__((address_space(3))) svoid_t;

__device__ __forceinline__ void gload_lds16(const void* gsrc, void* ldst) {
    __builtin_amdgcn_global_load_lds((gvoid_t*)gsrc, (svoid_t*)ldst, 16, 0, 0);
}

__device__ __forceinline__ uint32_t pack4(int4 v) {
    uint32_t r = (uint32_t)(uint8_t)v.x;
    r |= (uint32_t)(uint8_t)v.y << 8;
    r |= (uint32_t)(uint8_t)v.z << 16;
    r |= (uint32_t)(uint8_t)v.w << 24;
    return r;
}

// ---------------------------------------------------------------------------
// int32 -> int8 pack (values already in int8 range; truncate low byte)
// ---------------------------------------------------------------------------
__global__ void convert_kernel(const int* __restrict__ src, int8_t* __restrict__ dst,
                               int n4) {
    int idx = blockIdx.x * blockDim.x + threadIdx.x;
    int stride = gridDim.x * blockDim.x;
    for (int i = idx; i < n4; i += stride) {
        int4 v = ((const int4*)src)[i];
        ((uint32_t*)dst)[i] = pack4(v);
    }
}

// ---------------------------------------------------------------------------
// staging helpers for a 128x64 int8 LDS tile
// ---------------------------------------------------------------------------
// packed int8 source (already offset by k0 bytes), row-major stride ldk bytes
__device__ __forceinline__ void stage_packed(const int8_t* src, size_t grow0, int ldk,
                                             int8_t* lds, int wid, int lane) {
    const int r0 = wid * 32;
    const int rl = lane >> 2;          // 0..15
    const int cb = (lane & 3) * 16;    // 0/16/32/48
    const size_t g = (grow0 + r0 + rl) * (size_t)ldk + cb;
    gload_lds16(src + g, &lds[r0 * 64]);
    gload_lds16(src + g + (size_t)16 * ldk, &lds[(r0 + 16) * 64]);
}

// raw int32 source; pack in registers, ds_write
__device__ __forceinline__ void stage_raw(const int* src, size_t grow0, int ldk, int k0,
                                          int8_t* lds, int wid, int lane) {
    const int r0 = wid * 32;
    const int rr = lane >> 4;          // 0..3
    const int c4 = (lane & 15) * 4;    // element col, 4 per lane
#pragma unroll
    for (int it = 0; it < 8; ++it) {
        const int r = r0 + it * 4 + rr;
        int4 v = *(const int4*)&src[(grow0 + r) * (size_t)ldk + k0 + c4];
        *(uint32_t*)&lds[r * 64 + c4] = pack4(v);
    }
}

// ---------------------------------------------------------------------------
// Kernel 1: fused gate+up GEMM + dequant + SiLU*u + requant -> hq int8 [T,I]
// 128x128 tile, BK=64, 4 waves (2x2), mfma_i32_16x16x64_i8, 4x4 frags/wave.
// ---------------------------------------------------------------------------
template<bool PACKED>
__global__ __launch_bounds__(256, 2)
void gateup_kernel(const void* xp, const void* gwp, const void* uwp,
                   const float* __restrict__ galpha, const float* __restrict__ gbias,
                   const float* __restrict__ ualpha, const float* __restrict__ ubias,
                   const float* __restrict__ scale_p, int8_t* __restrict__ hq)
{
    __shared__ __align__(16) int8_t lsA[128 * 64];
    __shared__ __align__(16) int8_t lsG[128 * 64];
    __shared__ __align__(16) int8_t lsU[128 * 64];

    const int bid = blockIdx.x;
    const int mt = bid & 31;      // 32 M tiles
    const int nt = bid >> 5;      // 86 N tiles
    const int m0 = mt * 128;
    const int n0 = nt * 128;

    const int tid  = threadIdx.x;
    const int lane = tid & 63;
    const int wid  = tid >> 6;
    const int wr   = wid >> 1;
    const int wc   = wid & 1;

    i32x4 accg[4][4], accu[4][4];
#pragma unroll
    for (int m = 0; m < 4; ++m)
#pragma unroll
        for (int n = 0; n < 4; ++n) {
            accg[m][n] = i32x4{0, 0, 0, 0};
            accu[m][n] = i32x4{0, 0, 0, 0};
        }

    const int lr = lane & 15;
    const int lk = (lane >> 4) * 16;
    const int aoff0 = (wr * 64 + lr) * 64 + lk;
    const int boff0 = (wc * 64 + lr) * 64 + lk;

    for (int kt = 0; kt < H_DIM / 64; ++kt) {
        const int k0 = kt * 64;
        if (PACKED) {
            stage_packed((const int8_t*)xp + k0, m0, H_DIM, lsA, wid, lane);
            stage_packed((const int8_t*)gwp + k0, n0, H_DIM, lsG, wid, lane);
            stage_packed((const int8_t*)uwp + k0, n0, H_DIM, lsU, wid, lane);
        } else {
            stage_raw((const int*)xp, m0, H_DIM, k0, lsA, wid, lane);
            stage_raw((const int*)gwp, n0, H_DIM, k0, lsG, wid, lane);
            stage_raw((const int*)uwp, n0, H_DIM, k0, lsU, wid, lane);
        }
        __syncthreads();
        i32x4 af[4], bgf[4], buf_[4];
#pragma unroll
        for (int m = 0; m < 4; ++m)
            af[m] = *(const i32x4*)&lsA[aoff0 + m * 16 * 64];
#pragma unroll
        for (int n = 0; n < 4; ++n) {
            bgf[n]  = *(const i32x4*)&lsG[boff0 + n * 16 * 64];
            buf_[n] = *(const i32x4*)&lsU[boff0 + n * 16 * 64];
        }
#pragma unroll
        for (int m = 0; m < 4; ++m)
#pragma unroll
            for (int n = 0; n < 4; ++n) {
                accg[m][n] = __builtin_amdgcn_mfma_i32_16x16x64_i8(af[m], bgf[n], accg[m][n], 0, 0, 0);
                accu[m][n] = __builtin_amdgcn_mfma_i32_16x16x64_i8(af[m], buf_[n], accu[m][n], 0, 0, 0);
            }
        __syncthreads();
    }

    // epilogue: dequant, SwiGLU, requant
    const float scale = *scale_p;
#pragma unroll
    for (int n = 0; n < 4; ++n) {
        const int col = n0 + wc * 64 + n * 16 + lr;
        const float ga = galpha[col], gb = gbias[col];
        const float ua = ualpha[col], ub = ubias[col];
#pragma unroll
        for (int m = 0; m < 4; ++m) {
            const int row0 = m0 + wr * 64 + m * 16 + (lane >> 4) * 4;
#pragma unroll
            for (int j = 0; j < 4; ++j) {
                float g = (float)accg[m][n][j] * ga + gb;
                float u = (float)accu[m][n][j] * ua + ub;
                float s = 1.0f / (1.0f + __expf(-g));
                float h = g * s * u;
                float q = rintf(h / scale);
                q = fminf(127.0f, fmaxf(-128.0f, q));
                hq[(size_t)(row0 + j) * I_DIM + col] = (int8_t)q;
            }
        }
    }
}

// ---------------------------------------------------------------------------
// Kernel 2: down GEMM (hq int8 x down_w) + dequant -> fp32 out [T,H]
// ---------------------------------------------------------------------------
template<bool PACKED_B>
__global__ __launch_bounds__(256, 2)
void down_kernel(const int8_t* __restrict__ hq, const void* dwp,
                 const float* __restrict__ dalpha, const float* __restrict__ dbias,
                 float* __restrict__ out)
{
    __shared__ __align__(16) int8_t lsA[128 * 64];
    __shared__ __align__(16) int8_t lsB[128 * 64];

    const int bid = blockIdx.x;
    const int mt = bid & 31;
    const int nt = bid >> 5;      // 0..31
    const int m0 = mt * 128;
    const int n0 = nt * 128;

    const int tid  = threadIdx.x;
    const int lane = tid & 63;
    const int wid  = tid >> 6;
    const int wr   = wid >> 1;
    const int wc   = wid & 1;

    i32x4 acc[4][4];
#pragma unroll
    for (int m = 0; m < 4; ++m)
#pragma unroll
        for (int n = 0; n < 4; ++n) acc[m][n] = i32x4{0, 0, 0, 0};

    const int lr = lane & 15;
    const int lk = (lane >> 4) * 16;
    const int aoff0 = (wr * 64 + lr) * 64 + lk;
    const int boff0 = (wc * 64 + lr) * 64 + lk;

    for (int kt = 0; kt < I_DIM / 64; ++kt) {   // 172 iterations
        const int k0 = kt * 64;
        stage_packed(hq + k0, m0, I_DIM, lsA, wid, lane);
        if (PACKED_B) {
            stage_packed((const int8_t*)dwp + k0, n0, I_DIM, lsB, wid, lane);
        } else {
            stage_raw((const int*)dwp, n0, I_DIM, k0, lsB, wid, lane);
        }
        __syncthreads();
        i32x4 af[4], bf[4];
#pragma unroll
        for (int m = 0; m < 4; ++m)
            af[m] = *(const i32x4*)&lsA[aoff0 + m * 16 * 64];
#pragma unroll
        for (int n = 0; n < 4; ++n)
            bf[n] = *(const i32x4*)&lsB[boff0 + n * 16 * 64];
#pragma unroll
        for (int m = 0; m < 4; ++m)
#pragma unroll
            for (int n = 0; n < 4; ++n)
                acc[m][n] = __builtin_amdgcn_mfma_i32_16x16x64_i8(af[m], bf[n], acc[m][n], 0, 0, 0);
        __syncthreads();
    }

#pragma unroll
    for (int n = 0; n < 4; ++n) {
        const int col = n0 + wc * 64 + n * 16 + lr;
        const float da = dalpha[col], db = dbias[col];
#pragma unroll
        for (int m = 0; m < 4; ++m) {
            const int row0 = m0 + wr * 64 + m * 16 + (lane >> 4) * 4;
#pragma unroll
            for (int j = 0; j < 4; ++j) {
                out[(size_t)(row0 + j) * H_DIM + col] = (float)acc[m][n][j] * da + db;
            }
        }
    }
}

extern "C" void kernel_launch(void* const* d_in, const int* in_sizes, int n_in,
                              void* d_out, int out_size, void* d_ws, size_t ws_size,
                              hipStream_t stream) {
    const int* x32  = (const int*)d_in[0];
    const int* gw32 = (const int*)d_in[1];
    const int* uw32 = (const int*)d_in[2];
    const int* dw32 = (const int*)d_in[3];
    const float* ga = (const float*)d_in[4];
    const float* gb = (const float*)d_in[5];
    const float* ua = (const float*)d_in[6];
    const float* ub = (const float*)d_in[7];
    const float* da = (const float*)d_in[8];
    const float* db = (const float*)d_in[9];
    const float* sc = (const float*)d_in[10];
    float* out = (float*)d_out;

    const size_t SZ_X8 = (size_t)T_DIM * H_DIM;   // 16,777,216
    const size_t SZ_W  = (size_t)I_DIM * H_DIM;   // 45,088,768
    const size_t SZ_HQ = (size_t)T_DIM * I_DIM;   // 45,088,768
    const size_t FAST_TOTAL = 2 * SZ_W + SZ_HQ + SZ_X8;  // ~152 MB

    dim3 blk(256);
    if (ws_size >= FAST_TOTAL) {
        int8_t* gw8 = (int8_t*)d_ws;              // also reused for dw8 later
        int8_t* uw8 = gw8 + SZ_W;
        int8_t* hq  = uw8 + SZ_W;
        int8_t* x8  = hq + SZ_HQ;

        convert_kernel<<<dim3(2048), blk, 0, stream>>>(x32, x8, (int)(SZ_X8 / 4));
        convert_kernel<<<dim3(2048), blk, 0, stream>>>(gw32, gw8, (int)(SZ_W / 4));
        convert_kernel<<<dim3(2048), blk, 0, stream>>>(uw32, uw8, (int)(SZ_W / 4));
        gateup_kernel<true><<<dim3(32 * 86), blk, 0, stream>>>(
            x8, gw8, uw8, ga, gb, ua, ub, sc, hq);
        // dw8 overwrites gw8 region (gateup has finished reading it: same stream)
        int8_t* dw8 = gw8;
        convert_kernel<<<dim3(2048), blk, 0, stream>>>(dw32, dw8, (int)(SZ_W / 4));
        down_kernel<true><<<dim3(32 * 32), blk, 0, stream>>>(hq, dw8, da, db, out);
    } else {
        // fallback: hq only in ws; GEMMs read int32 and pack during staging
        int8_t* hq = (int8_t*)d_ws;
        gateup_kernel<false><<<dim3(32 * 86), blk, 0, stream>>>(
            x32, gw32, uw32, ga, gb, ua, ub, sc, hq);
        down_kernel<false><<<dim3(32 * 32), blk, 0, stream>>>(hq, dw32, da, db, out);
    }
}